// Round 6
// baseline (257.323 us; speedup 1.0000x reference)
//
#include <hip/hip_runtime.h>
#include <hip/hip_bf16.h>

// Problem constants
#define BATCH 256
#define DIM   2048
#define NMEM  16384   // C_CAM * P
#define PCLS  2048
#define CCAM  8
#define KSEL  50
#define T_INV 14.285714285714285714f   // 1 / 0.07
#define NB2   2048    // tail-histogram bins

typedef __bf16 bf16x8 __attribute__((ext_vector_type(8)));
typedef float  f32x4  __attribute__((ext_vector_type(4)));

static __device__ __forceinline__ unsigned int f2bf(float f) {
  unsigned int u = __float_as_uint(f);
  return (u + 0x7FFFu + ((u >> 16) & 1u)) >> 16;   // RNE truncate to bf16
}
static __device__ __forceinline__ unsigned int pk2(float lo, float hi) {
  return f2bf(lo) | (f2bf(hi) << 16);
}
// tail-window binning
static __device__ __forceinline__ int binw(float x, float lo, float scale) {
  int b = (int)((x - lo) * scale);
  return b > (NB2 - 1) ? (NB2 - 1) : b;
}

// Packed-A addressing (bank-conflict-free, coalesced frag loads; R4-verified)
// [mf(16)][kc(64)][lane(64)][8 elems]; lane = (r&15) | (((c>>3)&3)<<4)
static __device__ __forceinline__ size_t pa_idx(int r, int c) {
  return (size_t)(r >> 4) * (size_t)(64 * 8 * (DIM / 32))   // 32768 per mf
       + (size_t)(c >> 5) * 512
       + (size_t)(((r & 15) | (((c >> 3) & 3) << 4))) * 8
       + (size_t)(c & 7);
}

// ---------------------------------------------------------------------------
// Kernel 1: row-normalize inputs, cast to bf16, write A pre-packed (unchanged)
// ---------------------------------------------------------------------------
__global__ __launch_bounds__(256) void norm_cast_kernel(
    const float* __restrict__ in, unsigned short* __restrict__ xpk) {
  __shared__ float red[256];
  const int b = blockIdx.x, t = threadIdx.x;
  const float4* row = (const float4*)(in + (size_t)b * DIM);
  float4 a0 = row[t];
  float4 a1 = row[t + 256];
  float ss = a0.x*a0.x + a0.y*a0.y + a0.z*a0.z + a0.w*a0.w
           + a1.x*a1.x + a1.y*a1.y + a1.z*a1.z + a1.w*a1.w;
  red[t] = ss; __syncthreads();
  for (int s = 128; s > 0; s >>= 1) { if (t < s) red[t] += red[t + s]; __syncthreads(); }
  const float rn = rsqrtf(red[0]);
  ushort4 o0, o1;
  o0.x = (unsigned short)f2bf(a0.x*rn); o0.y = (unsigned short)f2bf(a0.y*rn);
  o0.z = (unsigned short)f2bf(a0.z*rn); o0.w = (unsigned short)f2bf(a0.w*rn);
  o1.x = (unsigned short)f2bf(a1.x*rn); o1.y = (unsigned short)f2bf(a1.y*rn);
  o1.z = (unsigned short)f2bf(a1.z*rn); o1.w = (unsigned short)f2bf(a1.w*rn);
  *(ushort4*)&xpk[pa_idx(b, 4 * t)]         = o0;
  *(ushort4*)&xpk[pa_idx(b, 4 * (t + 256))] = o1;
}

// ---------------------------------------------------------------------------
// Kernel 2: logits = x(bf16) @ tempV^T — counted-vmcnt raw-barrier pipeline.
// R5 post-mortem: __syncthreads emits s_waitcnt vmcnt(0) -> every chunk
// barrier drained the just-issued prefetches; and wave tile 32x64 was
// LDS-read-bound (FLOP/ds_byte=32 < ~40 balance). Here:
//  - raw s_barrier + "s_waitcnt vmcnt(12)": the 12 loads issued THIS phase
//    (4 V + 8 A, counts fixed via clamped tail loads) stay in flight ACROSS
//    the barrier, aged one full phase; only the previous phase's 12 drain.
//  - lgkmcnt(0)+sched_barrier(0) before MFMAs (ds_read ordering, rule 18);
//    lgkmcnt(0) before each s_barrier (ds_write visibility).
//  - wave tile 64 rows x 32 cols: FLOP/ds_byte=64, MFMA:ds_read=4:1.
//  - B LDS in MFMA-frag order [frag(8)][lane(64)][8]: reads conflict-free.
// BM=128, BN=64, BK=64; 4 waves (2M x 2N); grid 512 = 2 blocks/CU.
// ---------------------------------------------------------------------------
#define BMH 128
#define BNW 64
#define BKC 64
#define NCH (DIM / BKC)   // 32 chunks = 32 phases

__global__ __launch_bounds__(256, 2) void gemm_kernel(
    const unsigned short* __restrict__ Xpk,  // packed A, 1MB, L2-resident
    const float* __restrict__ V,             // [16384][2048] fp32
    float* __restrict__ C) {                 // [256][16384] fp32
  __shared__ __align__(16) unsigned short Bf[2][8][512];   // 16 KB
  const int t    = threadIdx.x;
  const int lane = t & 63;
  const int wid  = t >> 6;
  const int widM = wid >> 1, widN = wid & 1;
  const int n0 = blockIdx.x * BNW;
  const int m0 = blockIdx.y * BMH;

  // V staging: thread t -> V row vr = t>>2, 4 x float4 at cols vc4 + g*16.
  // Per wave instr (fixed g): 16 rows x 64 B contiguous — coalesced.
  const int vr  = t >> 2;          // 0..63
  const int vc4 = (t & 3) * 4;     // float col base
  const float* Vp = V + (size_t)(n0 + vr) * DIM + vc4;
  const int wfr = vr & 15, wjn = vr >> 4;   // LDS frag-row targets

  // A-frag pointer: wave rows m0 + widM*64 -> mf = (m0>>4) + widM*4 + i
  const unsigned short* Apk = Xpk + (size_t)((m0 >> 4) + widM * 4) * 32768
                                  + (size_t)lane * 8;

  f32x4 acc[4][2];
#pragma unroll
  for (int i = 0; i < 4; i++)
#pragma unroll
    for (int j = 0; j < 2; j++) acc[i][j] = (f32x4){0.f, 0.f, 0.f, 0.f};

  bf16x8 aA[8], aB[8];     // A-frag ping-pong (all indices compile-time)
  float4 vA[4], vB[4];     // V staging ping-pong

#define LOADV(VS, ch)                                                         \
  {                                                                           \
    const int ck_ = (ch);                                                     \
    _Pragma("unroll")                                                         \
    for (int g = 0; g < 4; ++g)                                               \
      VS[g] = *(const float4*)(Vp + ck_ * BKC + g * 16);                      \
  }
#define LOADA(AS, ch)                                                         \
  {                                                                           \
    const int ck_ = (ch);                                                     \
    _Pragma("unroll")                                                         \
    for (int i = 0; i < 4; ++i)                                               \
      _Pragma("unroll")                                                       \
      for (int s = 0; s < 2; ++s)                                             \
        AS[i * 2 + s] = *(const bf16x8*)(Apk + (size_t)i * 32768              \
                                             + (size_t)(ck_ * 2 + s) * 512);  \
  }
#define WRITEB(buf, VS)                                                       \
  {                                                                           \
    _Pragma("unroll")                                                         \
    for (int g = 0; g < 4; ++g) {                                             \
      const int c_  = vc4 + g * 16;                                           \
      const int f_  = wjn * 2 + (c_ >> 5);                                    \
      const int sl_ = (((c_ & 31) >> 3) << 4) + wfr;                          \
      uint2 p_; p_.x = pk2(VS[g].x, VS[g].y); p_.y = pk2(VS[g].z, VS[g].w);   \
      *(uint2*)&Bf[buf][f_][sl_ * 8 + (c_ & 7)] = p_;                         \
    }                                                                         \
  }
// ds_read current B frags; wait prev-phase loads (12 newer stay in flight);
// then the 16 MFMAs of this chunk.
#define COMPUTE(buf, AS)                                                      \
  {                                                                           \
    bf16x8 bF_[2][2];                                                         \
    _Pragma("unroll")                                                         \
    for (int j = 0; j < 2; ++j)                                               \
      _Pragma("unroll")                                                       \
      for (int s = 0; s < 2; ++s)                                             \
        bF_[j][s] = *(const bf16x8*)&Bf[buf][(widN * 2 + j) * 2 + s]          \
                                       [(size_t)lane * 8];                    \
    asm volatile("s_waitcnt vmcnt(12) lgkmcnt(0)" ::: "memory");              \
    __builtin_amdgcn_sched_barrier(0);                                        \
    _Pragma("unroll")                                                         \
    for (int s = 0; s < 2; ++s)                                               \
      _Pragma("unroll")                                                       \
      for (int i = 0; i < 4; ++i)                                             \
        _Pragma("unroll")                                                     \
        for (int j = 0; j < 2; ++j)                                           \
          acc[i][j] = __builtin_amdgcn_mfma_f32_16x16x32_bf16(                \
              AS[i * 2 + s], bF_[j][s], acc[i][j], 0, 0, 0);                  \
  }

  // ---- prologue: B(0) -> buf0; issue V(1), A(0) to fly across barrier ----
  {
    float4 v0[4];
    LOADV(v0, 0);
    asm volatile("s_waitcnt vmcnt(0)" ::: "memory");
    WRITEB(0, v0);
  }
  LOADV(vA, 1);
  LOADA(aA, 0);
  asm volatile("s_waitcnt lgkmcnt(0)" ::: "memory");
  __builtin_amdgcn_s_barrier();

#pragma unroll 1
  for (int it = 0; it < NCH / 2; ++it) {
    const int P0 = 2 * it;
    // ---- even phase P0: compute chunk P0 (buf0, aA); vNext = vA = V(P0+1)
    LOADV(vB, min(P0 + 2, NCH - 1));       // V(P0+2), for next phase's write
    LOADA(aB, min(P0 + 1, NCH - 1));       // A(P0+1), next phase's MFMAs
    COMPUTE(0, aA);                        // waits vmcnt(12): drains vA,aA
    WRITEB(1, vA);                         // buf1 <- B(P0+1)
    asm volatile("s_waitcnt lgkmcnt(0)" ::: "memory");
    __builtin_amdgcn_s_barrier();
    // ---- odd phase P0+1: compute chunk P0+1 (buf1, aB); vNext = vB
    LOADV(vA, min(P0 + 3, NCH - 1));
    LOADA(aA, min(P0 + 2, NCH - 1));
    COMPUTE(1, aB);
    WRITEB(0, vB);                         // buf0 <- B(P0+2)
    asm volatile("s_waitcnt lgkmcnt(0)" ::: "memory");
    __builtin_amdgcn_s_barrier();
  }

  // epilogue: C/D layout col=lane&15, row=(lane>>4)*4+reg  [m89/m91 verified]
  const int cr = (lane >> 4) * 4;
  const int cc = lane & 15;
#pragma unroll
  for (int i = 0; i < 4; i++)
#pragma unroll
    for (int j = 0; j < 2; j++)
#pragma unroll
      for (int r = 0; r < 4; r++)
        C[(size_t)(m0 + widM * 64 + i * 16 + cr + r) * NMEM
          + (n0 + widN * 32 + j * 16 + cc)] = acc[i][j][r];
#undef LOADV
#undef LOADA
#undef WRITEB
#undef COMPUTE
}

// ---------------------------------------------------------------------------
// Kernel 3: per-row losses (unchanged for attribution).
// ---------------------------------------------------------------------------
__global__ __launch_bounds__(1024) void row_loss_kernel(
    const float* __restrict__ logits,
    const int* __restrict__ labels, const int* __restrict__ cams,
    float* __restrict__ ce_out, float* __restrict__ lossk_out) {
  __shared__ float ovs[CCAM];
  __shared__ float wredA[16], wredB[16];
  __shared__ int   hist[NB2];       // 8 KB
  __shared__ int   pint[256];
  __shared__ float bl[512];
  __shared__ int   bcount;
  __shared__ int   bstar_s, cabove_s, totwin_s;
  __shared__ float vmax_s;

  const int b = blockIdx.x, t = threadIdx.x;
  const int lane = t & 63, wid = t >> 6;
  const int cam = cams[b], label = labels[b];
  const float* row = logits + (size_t)b * NMEM;

  if (t < CCAM) ovs[t] = row[t * PCLS + label];

  float4 rr[4];
#pragma unroll
  for (int i = 0; i < 4; i++) rr[i] = *(const float4*)(row + (size_t)(t + 1024 * i) * 4);

  // ---- pass 1: masked max + intra exp-sum (own bank, unmasked) ----
  float vmax = -1e30f, Si = 0.f;
#pragma unroll
  for (int i = 0; i < 4; i++) {
    const int base = (t + 1024 * i) * 4;
    const float xs[4] = {rr[i].x, rr[i].y, rr[i].z, rr[i].w};
#pragma unroll
    for (int e = 0; e < 4; e++) {
      const int n = base + e;
      const float x = xs[e];
      if ((n >> 11) == cam) Si += __expf(x * T_INV);
      if ((n & (PCLS - 1)) != label) vmax = fmaxf(vmax, x);
    }
  }
#pragma unroll
  for (int off = 32; off > 0; off >>= 1) {
    vmax = fmaxf(vmax, __shfl_down(vmax, off));
    Si  += __shfl_down(Si, off);
  }
  if (lane == 0) { wredA[wid] = vmax; wredB[wid] = Si; }
  __syncthreads();
  if (t == 0) {
    float m = -1e30f, s = 0.f;
    for (int i = 0; i < 16; i++) { m = fmaxf(m, wredA[i]); s += wredB[i]; }
    vmax_s = m;
    ce_out[b] = logf(s) - ovs[cam] * T_INV;
    bcount = 0;
  }
  __syncthreads();

  // ---- pass 2: tail histogram with widening fallback ----
  float W = 0.0625f;
  float lo = 0.f, scale = 0.f;
  for (int att = 0; att < 6; ++att) {
    __syncthreads();
    for (int i = t; i < NB2; i += 1024) hist[i] = 0;
    __syncthreads();
    lo = vmax_s - W; scale = (float)NB2 / W;
#pragma unroll
    for (int i = 0; i < 4; i++) {
      const int base = (t + 1024 * i) * 4;
      const float xs[4] = {rr[i].x, rr[i].y, rr[i].z, rr[i].w};
#pragma unroll
      for (int e = 0; e < 4; e++) {
        const int n = base + e;
        const float x = xs[e];
        if (((n & (PCLS - 1)) != label) && x >= lo)
          atomicAdd(&hist[binw(x, lo, scale)], 1);
      }
    }
    __syncthreads();
    if (t < 256) {
      int ps = 0;
#pragma unroll
      for (int i = 0; i < 8; i++) ps += hist[t * 8 + i];
      pint[t] = ps;
    }
    __syncthreads();
    if (t == 0) {
      int tot = 0;
      for (int i = 0; i < 256; i++) tot += pint[i];
      totwin_s = tot;
      if (tot >= KSEL) {
        int cum = 0, bstar = 0, cab = 0;
        for (int tc = 255; tc >= 0; tc--) {
          if (cum + pint[tc] >= KSEL) {
            for (int bi = tc * 8 + 7; bi >= tc * 8; bi--) {
              int h = hist[bi];
              if (cum + h >= KSEL) { bstar = bi; cab = cum; break; }
              cum += h;
            }
            break;
          }
          cum += pint[tc];
        }
        bstar_s = bstar; cabove_s = cab;
      }
    }
    __syncthreads();
    if (totwin_s >= KSEL) break;
    W *= 8.f;
  }
  const int bstar = bstar_s;

  // ---- pass 3: sum exp over bins > b*, collect boundary bin ----
  float S2 = 0.f;
#pragma unroll
  for (int i = 0; i < 4; i++) {
    const int base = (t + 1024 * i) * 4;
    const float xs[4] = {rr[i].x, rr[i].y, rr[i].z, rr[i].w};
#pragma unroll
    for (int e = 0; e < 4; e++) {
      const int n = base + e;
      const float x = xs[e];
      if (((n & (PCLS - 1)) != label) && x >= lo) {
        const int bin = binw(x, lo, scale);
        if (bin > bstar) S2 += __expf(x * T_INV);
        else if (bin == bstar) {
          int p = atomicAdd(&bcount, 1);
          if (p < 512) bl[p] = x;
        }
      }
    }
  }
#pragma unroll
  for (int off = 32; off > 0; off >>= 1) S2 += __shfl_down(S2, off);
  if (lane == 0) wredB[wid] = S2;
  __syncthreads();

  if (t == 0) {
    float S2tot = 0.f;
    for (int i = 0; i < 16; i++) S2tot += wredB[i];
    const int need = KSEL - cabove_s;
    const int bc = min(bcount, 512);
    for (int r = 0; r < need; r++) {         // exact top-(need) of boundary bin
      float mx = -1e30f; int mi = 0;
      for (int i = 0; i < bc; i++) if (bl[i] > mx) { mx = bl[i]; mi = i; }
      S2tot += __expf(mx * T_INV);
      bl[mi] = -1e30f;
    }
    float sumo = 0.f;
#pragma unroll
    for (int c = 0; c < CCAM; c++) { S2tot += __expf(ovs[c] * T_INV); sumo += ovs[c]; }
    lossk_out[b] = logf(S2tot) - (sumo * T_INV) * (1.0f / CCAM);
  }
}

// ---------------------------------------------------------------------------
// Kernel 4: deterministic per-camera segment means -> 2 scalars.
// ---------------------------------------------------------------------------
__global__ __launch_bounds__(256) void finalize_kernel(
    const float* __restrict__ ce, const float* __restrict__ lossk,
    const int* __restrict__ cams, float* __restrict__ out) {
  __shared__ float ce_s[BATCH], lk_s[BATCH];
  __shared__ int   cam_s[BATCH];
  __shared__ float si[CCAM], sk[CCAM], cnt[CCAM];
  const int t = threadIdx.x;
  ce_s[t]  = ce[t];
  lk_s[t]  = lossk[t];
  cam_s[t] = cams[t];
  __syncthreads();
  if (t < CCAM) {
    float a = 0.f, b = 0.f; int n = 0;
    for (int i = 0; i < BATCH; i++) {
      if (cam_s[i] == t) { a += ce_s[i]; b += lk_s[i]; n++; }
    }
    si[t] = a; sk[t] = b; cnt[t] = (float)n;
  }
  __syncthreads();
  if (t == 0) {
    float li = 0.f, lk = 0.f;
    for (int c = 0; c < CCAM; c++) {
      if (cnt[c] > 0.f) { li += si[c] / cnt[c]; lk += sk[c] / cnt[c]; }
    }
    out[0] = li;
    out[1] = 0.5f * lk;
  }
}

// ---------------------------------------------------------------------------
extern "C" void kernel_launch(void* const* d_in, const int* in_sizes, int n_in,
                              void* d_out, int out_size, void* d_ws, size_t ws_size,
                              hipStream_t stream) {
  const float* inputs = (const float*)d_in[0];   // [256][2048]
  const int*   labels = (const int*)d_in[1];     // [256]
  const int*   cams   = (const int*)d_in[2];     // [256]
  const float* tempV  = (const float*)d_in[3];   // [16384][2048]
  float* out = (float*)d_out;

  char* ws = (char*)d_ws;
  unsigned short* xpk = (unsigned short*)ws;                       // 1 MB packed A
  float* logits       = (float*)(ws + (1u << 20));                 // 16 MB
  float* ce           = (float*)(ws + (1u << 20) + (16u << 20));   // 1 KB
  float* lossk        = (float*)(ws + (1u << 20) + (16u << 20) + 1024);

  norm_cast_kernel<<<BATCH, 256, 0, stream>>>(inputs, xpk);
  gemm_kernel<<<dim3(NMEM / BNW, BATCH / BMH), 256, 0, stream>>>(xpk, tempV, logits);
  row_loss_kernel<<<BATCH, 1024, 0, stream>>>(logits, labels, cams, ce, lossk);
  finalize_kernel<<<1, 256, 0, stream>>>(ce, lossk, cams, out);
}